// Round 3
// baseline (334.631 us; speedup 1.0000x reference)
//
#include <hip/hip_runtime.h>

// PatchMask: out[b,c,h,w] = x[b,c,h,w] * keep_mask[b, h/16, w/16]
// x: fp32 [64,3,512,512]  (192 MiB)   keep_mask: int32 [64,32,32] (256 KiB)
//
// Memory-bound streaming pass. Round-3 change (single variable):
// persistent grid-stride loop with grid capped at 2048 blocks
// (256 CU x 8 blocks/CU, Guideline 11) instead of 49,152 one-shot
// workgroups. Each thread handles 24 float4s -> compiler can keep
// multiple loads in flight per thread (ILP) and we pay workgroup
// dispatch cost 24x less often.
//   - float4 per lane (16B, coalescing sweet spot)
//   - mask and x loads issue independently (round-1 showed the
//     conditional-fetch variant serializes mask->x and regresses)
// Traffic: 192 MiB R + 192 MiB W + mask ~= 402 MB; ~64 us at the
// 6.3 TB/s demonstrated copy ceiling.

#define W_DIM 512
#define H_DIM 512
#define CH 3
#define PATCH 16

__global__ __launch_bounds__(256) void PatchMask_kernel(
    const float4* __restrict__ x,
    const int* __restrict__ mask,
    float4* __restrict__ out,
    int n4)
{
    int stride = gridDim.x * blockDim.x;          // 524,288 float4s = 8 MiB
    for (int i = blockIdx.x * blockDim.x + threadIdx.x; i < n4; i += stride) {
        int e = i << 2;                 // element index
        int w = e & (W_DIM - 1);        // 512 = 2^9
        int h = (e >> 9) & (H_DIM - 1);
        int bc = e >> 18;               // b*3 + c
        int b = bc / CH;                // magic-mul

        int mi = (b << 10) + ((h >> 4) << 5) + (w >> 4);  // mask [B,32,32]

        float4 v = x[i];                // issues in parallel with mask load
        if (mask[mi] == 0) {
            v.x = 0.f; v.y = 0.f; v.z = 0.f; v.w = 0.f;
        }
        out[i] = v;
    }
}

extern "C" void kernel_launch(void* const* d_in, const int* in_sizes, int n_in,
                              void* d_out, int out_size, void* d_ws, size_t ws_size,
                              hipStream_t stream) {
    const float4* x   = (const float4*)d_in[0];
    const int* mask   = (const int*)d_in[1];
    float4* out       = (float4*)d_out;

    int n4 = out_size >> 2;                      // 12,582,912 float4s
    int block = 256;
    int grid = 2048;                             // 256 CUs x 8 blocks/CU

    PatchMask_kernel<<<grid, block, 0, stream>>>(x, mask, out, n4);
}

// Round 4
// 328.337 us; speedup vs baseline: 1.0192x; 1.0192x over previous
//
#include <hip/hip_runtime.h>

// PatchMask: out[b,c,h,w] = x[b,c,h,w] * keep_mask[b, h/16, w/16]
// x: fp32 [64,3,512,512] (192 MiB)   keep_mask: int32 [64,32,32]
//
// Round-4 structure: ONE WAVE <-> ONE 16x16 PATCH.
//   64 lanes x float4 = 1 KiB = one patch (lane l: row=l>>2, 16B chunk=l&3).
//   Mask index is wave-uniform -> one scalar load + uniform branch:
//     masked waves (35%) issue ZERO x reads (whole 64B sectors skipped)
//     and just store zeros; kept waves copy with no per-lane mask
//     dependency (round-1's per-lane predicated load serialized mask->x
//     and regressed).
//   Same wave count / bytes-per-lane as the best one-shot variant
//   (196,608 waves, 16B/lane) -> TLP unchanged. One-shot launch kept:
//   round-3 showed grid-stride persistent blocks regress (-14us).
// Expected: FETCH_SIZE -12..-35% (line- vs sector-granularity),
// WRITE_SIZE unchanged, kernel ~75 -> 62-70 us.

#define CH 3
#define WAVES_PER_BLOCK 4

__global__ __launch_bounds__(256) void PatchMask_kernel(
    const float4* __restrict__ x,
    const int* __restrict__ mask,
    float4* __restrict__ out,
    int npatch)
{
    int lane = threadIdx.x & 63;
    int p = blockIdx.x * WAVES_PER_BLOCK + (threadIdx.x >> 6);  // patch id
    if (p >= npatch) return;            // wave-uniform guard

    int bc = p >> 10;                   // b*3 + c   (1024 patches per plane)
    int pr = (p >> 5) & 31;             // patch row
    int pc = p & 31;                    // patch col
    int b  = bc / CH;                   // magic-mul

    // mask [B,32,32] — index is wave-uniform; force scalar path
    int mi = __builtin_amdgcn_readfirstlane((b << 10) + (pr << 5) + pc);
    int m  = mask[mi];                  // uniform address -> s_load

    // float4 index: plane stride 2^16, row stride 2^7 (512 floats / 4)
    int row = lane >> 2;                // 0..15 within patch
    int c4  = lane & 3;                 // 0..3 (16B chunks across 64B row)
    int i4 = (bc << 16) + (((pr << 4) + row) << 7) + (pc << 2) + c4;

    if (m == 0) {
        float4 z; z.x = 0.f; z.y = 0.f; z.z = 0.f; z.w = 0.f;
        out[i4] = z;                    // no x read at all for masked patches
    } else {
        out[i4] = x[i4];
    }
}

extern "C" void kernel_launch(void* const* d_in, const int* in_sizes, int n_in,
                              void* d_out, int out_size, void* d_ws, size_t ws_size,
                              hipStream_t stream) {
    const float4* x   = (const float4*)d_in[0];
    const int* mask   = (const int*)d_in[1];
    float4* out       = (float4*)d_out;

    // out_size is the f32 element count (50,331,648); 256 px per patch
    int npatch = out_size >> 8;                          // 196,608 patches
    int block  = 256;                                    // 4 waves/block
    int grid   = (npatch + WAVES_PER_BLOCK - 1) / WAVES_PER_BLOCK;  // 49,152

    PatchMask_kernel<<<grid, block, 0, stream>>>(x, mask, out, npatch);
}